// Round 11
// baseline (173.949 us; speedup 1.0000x reference)
//
#include <hip/hip_runtime.h>
#include <hip/hip_bf16.h>

// EmbedLayerUpdate, round 10 (round-8 skeleton + coalesced A loader,
// per-block k-rotation, 3 blocks/CU). All loads compiler-visible.
// Block = 64 rows x 2 batches, 4 waves = k-half x batch, 512 blocks.
// B = frag-ordered bf16 in ws (global->VGPR). A = fp32->cvt->swizzled LDS dbuf.

#define DOUT 4096
typedef __bf16 bf16x8 __attribute__((ext_vector_type(8)));
typedef __bf16 bf16x4 __attribute__((ext_vector_type(4)));
typedef float  f32x4  __attribute__((ext_vector_type(4)));

__device__ __forceinline__ __bf16 bfc(float x) { return (__bf16)x; }

__device__ __forceinline__ bf16x8 cvt8(const float4 a, const float4 b) {
    bf16x8 r;
    r[0]=bfc(a.x); r[1]=bfc(a.y); r[2]=bfc(a.z); r[3]=bfc(a.w);
    r[4]=bfc(b.x); r[5]=bfc(b.y); r[6]=bfc(b.z); r[7]=bfc(b.w);
    return r;
}
__device__ __forceinline__ bf16x4 cvt4(const float4 a) {
    bf16x4 r;
    r[0]=bfc(a.x); r[1]=bfc(a.y); r[2]=bfc(a.z); r[3]=bfc(a.w);
    return r;
}

// 128-byte rows (64 bf16): XOR-swizzle 16B chunks with row&7
__device__ __forceinline__ int aoff(int r, int c16) {
    return (r << 7) + ((c16 << 4) ^ ((r & 7) << 4));
}

#define WS_MU0 0
#define WS_MU1 (4u << 20)
#define WS_SM  (12u << 20)

// ---- prepass: mu0 -> frag-ordered bf16 tiles; small weights -> bf16 ----
__global__ __launch_bounds__(256)
void prepass_kernel(const float* __restrict__ mu0, const float* __restrict__ fc11W,
                    const float* __restrict__ fc2W, const float* __restrict__ fc21W,
                    char* __restrict__ ws)
{
    const int blk = blockIdx.x, t = threadIdx.x;
    if (blk < 512) {
        const int b = blk >> 5, kt = blk & 31;
        const int p = t & 63, kc = t >> 6;       // kc 0..3: 16 k each
        const float* src = mu0 + ((size_t)b * 2048 + kt * 64 + kc * 16) * 64 + p;
        char* tile = ws + WS_MU0 + ((size_t)b * 32 + kt) * 8192;
        float v[16];
        #pragma unroll
        for (int i = 0; i < 16; ++i) v[i] = src[(size_t)i * 64];
        bf16x8 o0, o1;
        #pragma unroll
        for (int i = 0; i < 8; ++i) { o0[i] = bfc(v[i]); o1[i] = bfc(v[8 + i]); }
        const int n = p >> 4, ks = kc >> 1;
        const int l0 = (((kc & 1) * 2) << 4) | (p & 15);
        const int l1 = (((kc & 1) * 2 + 1) << 4) | (p & 15);
        *(bf16x8*)(tile + ks * 4096 + n * 1024 + l0 * 16) = o0;
        *(bf16x8*)(tile + ks * 4096 + n * 1024 + l1 * 16) = o1;
    } else {
        const int idx = (blk - 512) * 256 + t;
        __bf16* dst = (__bf16*)(ws + WS_SM);
        if (idx < 4096)        dst[idx] = bfc(fc11W[idx]);
        else if (idx < 12288)  dst[idx] = bfc(fc2W[idx - 4096]);
        else                   dst[idx] = bfc(fc21W[idx - 12288]);
    }
}

// A: wave-instruction = 4 contiguous 256B row segments (rows tid>>4 + 16q)
#define LOADA(dst, kt_) { const float* s_ = aSrc + (size_t)(kt_) * 64;          \
    dst[0] = *(const float4*)s_;                                                \
    dst[1] = *(const float4*)(s_ + 16 * K);                                     \
    dst[2] = *(const float4*)(s_ + 32 * K);                                     \
    dst[3] = *(const float4*)(s_ + 48 * K); }

#define WRITEA(buf, set) {                                                      \
    *(bf16x4*)((buf) + awb)        = cvt4(set[0]);                              \
    *(bf16x4*)((buf) + awb + 2048) = cvt4(set[1]);                              \
    *(bf16x4*)((buf) + awb + 4096) = cvt4(set[2]);                              \
    *(bf16x4*)((buf) + awb + 6144) = cvt4(set[3]); }

#define LOADB(dst, kt_) { const char* bp_ = bW + (size_t)(kt_) * 8192 + lane * 16; \
    _Pragma("unroll")                                                            \
    for (int n_ = 0; n_ < 4; ++n_) dst[n_] = *(const bf16x8*)(bp_ + n_ * 1024); }

#define MFMAS(Abuf, bset) {                                                      \
    bf16x8 af_[4];                                                               \
    _Pragma("unroll")                                                            \
    for (int m_ = 0; m_ < 4; ++m_)                                               \
        af_[m_] = *(const bf16x8*)((Abuf) + aoff(m_ * 16 + lr, khc + lg));       \
    __builtin_amdgcn_s_setprio(1);                                               \
    _Pragma("unroll")                                                            \
    for (int m_ = 0; m_ < 4; ++m_)                                               \
        _Pragma("unroll")                                                        \
        for (int n_ = 0; n_ < 4; ++n_)                                           \
            acc[m_][n_] = __builtin_amdgcn_mfma_f32_16x16x32_bf16(               \
                af_[m_], bset[n_], acc[m_][n_], 0, 0, 0);                        \
    __builtin_amdgcn_s_setprio(0); }

// ---------------- layer kernel ----------------
template <int K, bool WRITE_T>
__global__ __launch_bounds__(256, 3)
void layer_kernel(const float* __restrict__ W, const float* __restrict__ bias,
                  const char* __restrict__ wsB,
                  const float* __restrict__ lb, const float* __restrict__ ub,
                  const float* __restrict__ ps, const float* __restrict__ ss,
                  const float* __restrict__ mask,
                  const float* __restrict__ fc1W, const float* __restrict__ fc1b,
                  const __bf16* __restrict__ fc11bf, const float* __restrict__ fc11b,
                  const __bf16* __restrict__ fc2bf, const float* __restrict__ fc2b,
                  const __bf16* __restrict__ fc21bf, const float* __restrict__ fc21b,
                  float* __restrict__ out, char* __restrict__ wsT)
{
    constexpr int NT = K / 64;
    __shared__ __align__(16) char lds[49152];
    // main: A dbuf @0/8K. post-loop: red @0..32K; pre @32K..48K;
    // T @0..16K; H @16K..32K; U -> T region; WT staging -> H region.
    char* const pre   = lds + 32768;
    char* const T_lds = lds;
    char* const H_lds = lds + 16384;

    const int tid = threadIdx.x;
    const int lane = tid & 63, wv = tid >> 6;
    const int kh = wv >> 1, bn = wv & 1;         // k-half, batch-in-block
    const int khc = kh * 4;
    const int lr = lane & 15, lg = lane >> 4;

    // XCD swizzle: 512 = 8 xcd * 64; XCD gets 8 panels x 8 bgroups
    const int id = blockIdx.x;
    const int vid = (id & 7) * 64 + (id >> 3);
    const int panel = vid >> 3;                  // 0..63 (64-row panels)
    const int bgroup = vid & 7;                  // 0..7 (2 batches each)
    const int orow0 = panel * 64;
    const int batch0 = bgroup * 2;

    const char* bW = wsB + ((size_t)(batch0 + bn) * NT) * 8192 + khc * 1024;

    // A loader: base row = tid>>4 (+16 per pass), col = tid&15 (float4).
    // Per wave-instruction: 4 contiguous 256B segments (coalesced).
    const int arow = tid >> 4, acol = tid & 15;
    const float* aSrc = W + (size_t)(orow0 + arow) * K + acol * 4;
    const int awb = arow * 128 + ((acol * 8) ^ ((arow & 7) << 4));

    // per-block k-loop rotation (decorrelate block phases); wraps mod NT
    const int t0 = vid & (NT - 1);
#define KT(i_) ((t0 + (i_)) & (NT - 1))

    const f32x4 z = {0.f, 0.f, 0.f, 0.f};
    f32x4 acc[4][4];
    #pragma unroll
    for (int m = 0; m < 4; ++m)
        #pragma unroll
        for (int n = 0; n < 4; ++n) acc[m][n] = z;

    float4 aR0[4], aR1[4];
    bf16x8 bR0[4], bR1[4];

    // ---------- prologue ----------
    LOADA(aR0, KT(0)); LOADB(bR0, KT(0));
    LOADA(aR1, KT(1)); LOADB(bR1, KT(1));
    asm volatile("s_waitcnt vmcnt(8)" ::: "memory");   // aR0,bR0 landed
    WRITEA(lds, aR0);
    asm volatile("s_waitcnt lgkmcnt(0)" ::: "memory");
    asm volatile("s_barrier" ::: "memory");

    // ---------- main loop (unroll 2, static reg sets, wrapped prefetch) ----------
    for (int t = 0; t < NT; t += 2) {
        // even: consume ab0/bR0
        LOADA(aR0, KT(t + 2));
        MFMAS(lds, bR0);
        LOADB(bR0, KT(t + 2));
        asm volatile("s_waitcnt vmcnt(8)" ::: "memory");
        WRITEA(lds + 8192, aR1);                       // A(t+1)
        asm volatile("s_waitcnt lgkmcnt(0)" ::: "memory");
        asm volatile("s_barrier" ::: "memory");
        // odd: consume ab1/bR1
        LOADA(aR1, KT(t + 3));
        MFMAS(lds + 8192, bR1);
        LOADB(bR1, KT(t + 3));
        asm volatile("s_waitcnt vmcnt(8)" ::: "memory");
        WRITEA(lds, aR0);                              // A(t+2)
        asm volatile("s_waitcnt lgkmcnt(0)" ::: "memory");
        asm volatile("s_barrier" ::: "memory");
    }
    __syncthreads();

    // ---------- k-half reduction; pre+bias -> per-batch [64][64] bf16 ----------
    if (kh == 0) {
        #pragma unroll
        for (int m = 0; m < 4; ++m)
            #pragma unroll
            for (int n = 0; n < 4; ++n)
                *(f32x4*)(lds + bn * 16384 + ((m * 4 + n) * 64 + lane) * 16) = acc[m][n];
    }
    __syncthreads();
    if (kh == 1) {
        #pragma unroll
        for (int m = 0; m < 4; ++m)
            #pragma unroll
            for (int n = 0; n < 4; ++n)
                acc[m][n] += *(const f32x4*)(lds + bn * 16384 + ((m * 4 + n) * 64 + lane) * 16);
        char* const dst = pre + bn * 8192;
        #pragma unroll
        for (int m = 0; m < 4; ++m)
            #pragma unroll
            for (int n = 0; n < 4; ++n) {
                const int col = n * 16 + lr;
                #pragma unroll
                for (int r = 0; r < 4; ++r) {
                    const int row = m * 16 + lg * 4 + r;
                    const float bs = bias[orow0 + row];
                    *(__bf16*)(dst + row * 128 + ((2 * col) ^ ((row & 7) << 4))) =
                        bfc(acc[m][n][r] + bs);
                }
            }
    }
    __syncthreads();

    // ---------- epilogue on 128 rows (2 batches x 64) ----------
    const int wm = wv >> 1, wn = wv & 1;

    // T = relu(info @ fc1W^T + fc1b) -> T_lds [128][64] swizzled
    {
        const int row = tid >> 1;                 // 0..127
        const int j0 = (tid & 1) * 32;
        const int bb = batch0 + (row >> 6);
        const int g = bb * DOUT + orow0 + (row & 63);
        const float lv = lb[g], uv = ub[g];
        const float lt = fminf(lv, 0.f), ut = fmaxf(uv, 0.f);
        const float diff = ut - lt;
        const float urr = ut / (diff + 1e-8f);
        const float lrr = 1.f - urr, i3 = ps[g], i4 = ss[g];
        #pragma unroll
        for (int c = 0; c < 4; ++c) {
            bf16x8 v;
            #pragma unroll
            for (int jj = 0; jj < 8; ++jj) {
                const int j = j0 + c * 8 + jj;
                const float* w = fc1W + j * 5;
                const float tv = fc1b[j] + urr * w[0] + lrr * w[1] + diff * w[2]
                               + i3 * w[3] + i4 * w[4];
                v[jj] = bfc(fmaxf(tv, 0.f));
            }
            *(bf16x8*)(T_lds + aoff(row, (j0 >> 3) + c)) = v;
        }
    }
    __syncthreads();

    // H = T @ fc11W^T + fc11b -> per-batch H tiles
    {
        f32x4 hacc[4][2];
        #pragma unroll
        for (int m = 0; m < 4; ++m) { hacc[m][0] = z; hacc[m][1] = z; }
        #pragma unroll
        for (int ks = 0; ks < 2; ++ks) {
            bf16x8 a[4];
            #pragma unroll
            for (int m = 0; m < 4; ++m)
                a[m] = *(const bf16x8*)(T_lds + aoff(wm * 64 + m * 16 + lr, ks * 4 + lg));
            #pragma unroll
            for (int n = 0; n < 2; ++n) {
                const int j = wn * 32 + n * 16 + lr;
                const bf16x8 bw = *(const bf16x8*)(fc11bf + (size_t)j * 64 + ks * 32 + lg * 8);
                #pragma unroll
                for (int m = 0; m < 4; ++m)
                    hacc[m][n] = __builtin_amdgcn_mfma_f32_16x16x32_bf16(a[m], bw, hacc[m][n], 0, 0, 0);
            }
        }
        char* const Hq = H_lds + wm * 8192;
        #pragma unroll
        for (int n = 0; n < 2; ++n) {
            const int j = wn * 32 + n * 16 + lr;
            const float bj = fc11b[j];
            #pragma unroll
            for (int m = 0; m < 4; ++m)
                #pragma unroll
                for (int r = 0; r < 4; ++r) {
                    const int row = m * 16 + lg * 4 + r;   // local 0..63
                    *(__bf16*)(Hq + row * 128 + ((2 * j) ^ ((row & 7) << 4))) =
                        bfc(hacc[m][n][r] + bj);
                }
        }
    }
    __syncthreads();

    // U = relu([pre|H] @ fc2W^T + fc2b) -> T region (T dead)
    {
        f32x4 uacc[4][2];
        #pragma unroll
        for (int m = 0; m < 4; ++m) { uacc[m][0] = z; uacc[m][1] = z; }
        #pragma unroll
        for (int ks = 0; ks < 4; ++ks) {
            const char* base = ((ks < 2) ? pre : H_lds) + wm * 8192;
            const int kb = ((ks & 1) * 64 + lg * 16);
            bf16x8 a[4];
            #pragma unroll
            for (int m = 0; m < 4; ++m) {
                const int row = m * 16 + lr;
                a[m] = *(const bf16x8*)(base + row * 128 + (kb ^ ((row & 7) << 4)));
            }
            #pragma unroll
            for (int n = 0; n < 2; ++n) {
                const int j = wn * 32 + n * 16 + lr;
                const bf16x8 bw = *(const bf16x8*)(fc2bf + (size_t)j * 128 + ks * 32 + lg * 8);
                #pragma unroll
                for (int m = 0; m < 4; ++m)
                    uacc[m][n] = __builtin_amdgcn_mfma_f32_16x16x32_bf16(a[m], bw, uacc[m][n], 0, 0, 0);
            }
        }
        __syncthreads();
        #pragma unroll
        for (int n = 0; n < 2; ++n) {
            const int j = wn * 32 + n * 16 + lr;
            const float bj = fc2b[j];
            #pragma unroll
            for (int m = 0; m < 4; ++m)
                #pragma unroll
                for (int r = 0; r < 4; ++r) {
                    const int row = wm * 64 + m * 16 + lg * 4 + r;   // 0..127
                    *(__bf16*)(T_lds + row * 128 + ((2 * j) ^ ((row & 7) << 4))) =
                        bfc(fmaxf(uacc[m][n][r] + bj, 0.f));
                }
        }
    }
    __syncthreads();

    // out = (U @ fc21W^T + fc21b) * mask ; WT staging -> H region
    {
        f32x4 oacc[4][2];
        #pragma unroll
        for (int m = 0; m < 4; ++m) { oacc[m][0] = z; oacc[m][1] = z; }
        #pragma unroll
        for (int ks = 0; ks < 2; ++ks) {
            bf16x8 a[4];
            #pragma unroll
            for (int m = 0; m < 4; ++m)
                a[m] = *(const bf16x8*)(T_lds + aoff(wm * 64 + m * 16 + lr, ks * 4 + lg));
            #pragma unroll
            for (int n = 0; n < 2; ++n) {
                const int j = wn * 32 + n * 16 + lr;
                const bf16x8 bw = *(const bf16x8*)(fc21bf + (size_t)j * 64 + ks * 32 + lg * 8);
                #pragma unroll
                for (int m = 0; m < 4; ++m)
                    oacc[m][n] = __builtin_amdgcn_mfma_f32_16x16x32_bf16(a[m], bw, oacc[m][n], 0, 0, 0);
            }
        }
        const int bb = batch0 + wm;
        #pragma unroll
        for (int n = 0; n < 2; ++n) {
            const int j = wn * 32 + n * 16 + lr;
            const float bj = fc21b[j];
            #pragma unroll
            for (int m = 0; m < 4; ++m)
                #pragma unroll
                for (int r = 0; r < 4; ++r) {
                    const int row = m * 16 + lg * 4 + r;    // local 0..63
                    const int g = bb * DOUT + orow0 + row;
                    const float o = (oacc[m][n][r] + bj) * mask[g];
                    out[(size_t)g * 64 + j] = o;
                    if (WRITE_T)
                        *(__bf16*)(H_lds + wm * 8192 + j * 128 +
                                   ((2 * row) ^ ((j & 7) << 4))) = bfc(o);
                }
        }
    }
    if (WRITE_T) {
        __syncthreads();
        // emit frag-ordered tiles: 2 batches x 512 chunks
        #pragma unroll
        for (int i = 0; i < 4; ++i) {
            const int idx = i * 256 + tid;          // 0..1023
            const int qq = idx >> 9, rr = idx & 511;
            const int ks = rr >> 8, n = (rr >> 6) & 3, ln = rr & 63;
            const int j = n * 16 + (ln & 15);
            const int k = ks * 32 + (ln >> 4) * 8;
            const bf16x8 v = *(const bf16x8*)(H_lds + qq * 8192 + j * 128 +
                                              ((2 * k) ^ ((j & 7) << 4)));
            const int bb = batch0 + qq;
            *(bf16x8*)(wsT + ((size_t)bb * 64 + panel) * 8192 +
                       ks * 4096 + n * 1024 + ln * 16) = v;
        }
    }
#undef KT
}

extern "C" void kernel_launch(void* const* d_in, const int* in_sizes, int n_in,
                              void* d_out, int out_size, void* d_ws, size_t ws_size,
                              hipStream_t stream) {
    const float* mu0   = (const float*)d_in[0];
    const float* lb1   = (const float*)d_in[1];
    const float* ub1   = (const float*)d_in[2];
    const float* lb2   = (const float*)d_in[3];
    const float* ub2   = (const float*)d_in[4];
    const float* ps1   = (const float*)d_in[5];
    const float* ss1   = (const float*)d_in[6];
    const float* ps2   = (const float*)d_in[7];
    const float* ss2   = (const float*)d_in[8];
    const float* mask1 = (const float*)d_in[9];
    const float* mask2 = (const float*)d_in[10];
    const float* W1    = (const float*)d_in[11];
    const float* b1    = (const float*)d_in[12];
    const float* W2    = (const float*)d_in[13];
    const float* b2    = (const float*)d_in[14];
    const float* fc1W  = (const float*)d_in[15];
    const float* fc1b  = (const float*)d_in[16];
    const float* fc11W = (const float*)d_in[17];
    const float* fc11b = (const float*)d_in[18];
    const float* fc2W  = (const float*)d_in[19];
    const float* fc2b  = (const float*)d_in[20];
    const float* fc21W = (const float*)d_in[21];
    const float* fc21b = (const float*)d_in[22];

    char* ws = (char*)d_ws;
    float* mu1 = (float*)d_out;
    float* mu2 = (float*)d_out + (size_t)16 * 4096 * 64;
    const __bf16* fc11bf = (const __bf16*)(ws + WS_SM);
    const __bf16* fc2bf  = (const __bf16*)(ws + WS_SM) + 4096;
    const __bf16* fc21bf = (const __bf16*)(ws + WS_SM) + 12288;

    prepass_kernel<<<576, 256, 0, stream>>>(mu0, fc11W, fc2W, fc21W, ws);

    layer_kernel<2048, true><<<512, 256, 0, stream>>>(
        W1, b1, ws + WS_MU0, lb1, ub1, ps1, ss1, mask1,
        fc1W, fc1b, fc11bf, fc11b, fc2bf, fc2b, fc21bf, fc21b,
        mu1, ws + WS_MU1);

    layer_kernel<4096, false><<<512, 256, 0, stream>>>(
        W2, b2, ws + WS_MU1, lb2, ub2, ps2, ss2, mask2,
        fc1W, fc1b, fc11bf, fc11b, fc2bf, fc2b, fc21bf, fc21b,
        mu2, nullptr);
}

// Round 12
// 162.544 us; speedup vs baseline: 1.0702x; 1.0702x over previous
//
#include <hip/hip_runtime.h>
#include <hip/hip_bf16.h>

// EmbedLayerUpdate, round 11 (round-8 skeleton + coalesced A loader + 3/CU +
// PANEL-ONLY k-rotation: blocks sharing a W panel stay phase-locked (L2 reuse),
// different panels spread across k-phases (decorrelated HBM bursts)).
// Block = 64 rows x 2 batches, 4 waves = k-half x batch, 512 blocks.
// B = frag-ordered bf16 in ws (global->VGPR). A = fp32->cvt->swizzled LDS dbuf.

#define DOUT 4096
typedef __bf16 bf16x8 __attribute__((ext_vector_type(8)));
typedef __bf16 bf16x4 __attribute__((ext_vector_type(4)));
typedef float  f32x4  __attribute__((ext_vector_type(4)));

__device__ __forceinline__ __bf16 bfc(float x) { return (__bf16)x; }

__device__ __forceinline__ bf16x4 cvt4(const float4 a) {
    bf16x4 r;
    r[0]=bfc(a.x); r[1]=bfc(a.y); r[2]=bfc(a.z); r[3]=bfc(a.w);
    return r;
}

// 128-byte rows (64 bf16): XOR-swizzle 16B chunks with row&7
__device__ __forceinline__ int aoff(int r, int c16) {
    return (r << 7) + ((c16 << 4) ^ ((r & 7) << 4));
}

#define WS_MU0 0
#define WS_MU1 (4u << 20)
#define WS_SM  (12u << 20)

// ---- prepass: mu0 -> frag-ordered bf16 tiles; small weights -> bf16 ----
__global__ __launch_bounds__(256)
void prepass_kernel(const float* __restrict__ mu0, const float* __restrict__ fc11W,
                    const float* __restrict__ fc2W, const float* __restrict__ fc21W,
                    char* __restrict__ ws)
{
    const int blk = blockIdx.x, t = threadIdx.x;
    if (blk < 512) {
        const int b = blk >> 5, kt = blk & 31;
        const int p = t & 63, kc = t >> 6;       // kc 0..3: 16 k each
        const float* src = mu0 + ((size_t)b * 2048 + kt * 64 + kc * 16) * 64 + p;
        char* tile = ws + WS_MU0 + ((size_t)b * 32 + kt) * 8192;
        float v[16];
        #pragma unroll
        for (int i = 0; i < 16; ++i) v[i] = src[(size_t)i * 64];
        bf16x8 o0, o1;
        #pragma unroll
        for (int i = 0; i < 8; ++i) { o0[i] = bfc(v[i]); o1[i] = bfc(v[8 + i]); }
        const int n = p >> 4, ks = kc >> 1;
        const int l0 = (((kc & 1) * 2) << 4) | (p & 15);
        const int l1 = (((kc & 1) * 2 + 1) << 4) | (p & 15);
        *(bf16x8*)(tile + ks * 4096 + n * 1024 + l0 * 16) = o0;
        *(bf16x8*)(tile + ks * 4096 + n * 1024 + l1 * 16) = o1;
    } else {
        const int idx = (blk - 512) * 256 + t;
        __bf16* dst = (__bf16*)(ws + WS_SM);
        if (idx < 4096)        dst[idx] = bfc(fc11W[idx]);
        else if (idx < 12288)  dst[idx] = bfc(fc2W[idx - 4096]);
        else                   dst[idx] = bfc(fc21W[idx - 12288]);
    }
}

// A: wave-instruction = 4 contiguous 256B row segments (rows tid>>4 + 16q)
#define LOADA(dst, kt_) { const float* s_ = aSrc + (size_t)(kt_) * 64;          \
    dst[0] = *(const float4*)s_;                                                \
    dst[1] = *(const float4*)(s_ + 16 * K);                                     \
    dst[2] = *(const float4*)(s_ + 32 * K);                                     \
    dst[3] = *(const float4*)(s_ + 48 * K); }

#define WRITEA(buf, set) {                                                      \
    *(bf16x4*)((buf) + awb)        = cvt4(set[0]);                              \
    *(bf16x4*)((buf) + awb + 2048) = cvt4(set[1]);                              \
    *(bf16x4*)((buf) + awb + 4096) = cvt4(set[2]);                              \
    *(bf16x4*)((buf) + awb + 6144) = cvt4(set[3]); }

#define LOADB(dst, kt_) { const char* bp_ = bW + (size_t)(kt_) * 8192 + lane * 16; \
    _Pragma("unroll")                                                            \
    for (int n_ = 0; n_ < 4; ++n_) dst[n_] = *(const bf16x8*)(bp_ + n_ * 1024); }

#define MFMAS(Abuf, bset) {                                                      \
    bf16x8 af_[4];                                                               \
    _Pragma("unroll")                                                            \
    for (int m_ = 0; m_ < 4; ++m_)                                               \
        af_[m_] = *(const bf16x8*)((Abuf) + aoff(m_ * 16 + lr, khc + lg));       \
    __builtin_amdgcn_s_setprio(1);                                               \
    _Pragma("unroll")                                                            \
    for (int m_ = 0; m_ < 4; ++m_)                                               \
        _Pragma("unroll")                                                        \
        for (int n_ = 0; n_ < 4; ++n_)                                           \
            acc[m_][n_] = __builtin_amdgcn_mfma_f32_16x16x32_bf16(               \
                af_[m_], bset[n_], acc[m_][n_], 0, 0, 0);                        \
    __builtin_amdgcn_s_setprio(0); }

// ---------------- layer kernel ----------------
template <int K, bool WRITE_T>
__global__ __launch_bounds__(256, 3)
void layer_kernel(const float* __restrict__ W, const float* __restrict__ bias,
                  const char* __restrict__ wsB,
                  const float* __restrict__ lb, const float* __restrict__ ub,
                  const float* __restrict__ ps, const float* __restrict__ ss,
                  const float* __restrict__ mask,
                  const float* __restrict__ fc1W, const float* __restrict__ fc1b,
                  const __bf16* __restrict__ fc11bf, const float* __restrict__ fc11b,
                  const __bf16* __restrict__ fc2bf, const float* __restrict__ fc2b,
                  const __bf16* __restrict__ fc21bf, const float* __restrict__ fc21b,
                  float* __restrict__ out, char* __restrict__ wsT)
{
    constexpr int NT = K / 64;
    __shared__ __align__(16) char lds[49152];
    // main: A dbuf @0/8K. post-loop: red @0..32K; pre @32K..48K;
    // T @0..16K; H @16K..32K; U -> T region; WT staging -> H region.
    char* const pre   = lds + 32768;
    char* const T_lds = lds;
    char* const H_lds = lds + 16384;

    const int tid = threadIdx.x;
    const int lane = tid & 63, wv = tid >> 6;
    const int kh = wv >> 1, bn = wv & 1;         // k-half, batch-in-block
    const int khc = kh * 4;
    const int lr = lane & 15, lg = lane >> 4;

    // XCD swizzle: 512 = 8 xcd * 64; XCD gets 8 panels x 8 bgroups
    const int id = blockIdx.x;
    const int vid = (id & 7) * 64 + (id >> 3);
    const int panel = vid >> 3;                  // 0..63 (64-row panels)
    const int bgroup = vid & 7;                  // 0..7 (2 batches each)
    const int orow0 = panel * 64;
    const int batch0 = bgroup * 2;

    const char* bW = wsB + ((size_t)(batch0 + bn) * NT) * 8192 + khc * 1024;

    // A loader: base row = tid>>4 (+16 per pass), col = tid&15 (float4).
    // Per wave-instruction: 4 contiguous 256B segments (coalesced).
    const int arow = tid >> 4, acol = tid & 15;
    const float* aSrc = W + (size_t)(orow0 + arow) * K + acol * 4;
    const int awb = arow * 128 + ((acol * 8) ^ ((arow & 7) << 4));

    // PANEL-ONLY k-rotation: same panel (8 bgroup-blocks) = same phase (keeps
    // W L2 reuse + single HBM fetch); different panels = spread phases
    // (decorrelates HBM bursts). Wraps mod NT; fp32 acc is order-independent.
    const int t0 = (panel & 7) * (NT / 8);
#define KT(i_) ((t0 + (i_)) & (NT - 1))

    const f32x4 z = {0.f, 0.f, 0.f, 0.f};
    f32x4 acc[4][4];
    #pragma unroll
    for (int m = 0; m < 4; ++m)
        #pragma unroll
        for (int n = 0; n < 4; ++n) acc[m][n] = z;

    float4 aR0[4], aR1[4];
    bf16x8 bR0[4], bR1[4];

    // ---------- prologue ----------
    LOADA(aR0, KT(0)); LOADB(bR0, KT(0));
    LOADA(aR1, KT(1)); LOADB(bR1, KT(1));
    asm volatile("s_waitcnt vmcnt(8)" ::: "memory");   // aR0,bR0 landed
    WRITEA(lds, aR0);
    asm volatile("s_waitcnt lgkmcnt(0)" ::: "memory");
    asm volatile("s_barrier" ::: "memory");

    // ---------- main loop (unroll 2, static reg sets, wrapped prefetch) ----------
    for (int t = 0; t < NT; t += 2) {
        // even: consume ab0/bR0
        LOADA(aR0, KT(t + 2));
        MFMAS(lds, bR0);
        LOADB(bR0, KT(t + 2));
        asm volatile("s_waitcnt vmcnt(8)" ::: "memory");
        WRITEA(lds + 8192, aR1);                       // A(t+1)
        asm volatile("s_waitcnt lgkmcnt(0)" ::: "memory");
        asm volatile("s_barrier" ::: "memory");
        // odd: consume ab1/bR1
        LOADA(aR1, KT(t + 3));
        MFMAS(lds + 8192, bR1);
        LOADB(bR1, KT(t + 3));
        asm volatile("s_waitcnt vmcnt(8)" ::: "memory");
        WRITEA(lds, aR0);                              // A(t+2)
        asm volatile("s_waitcnt lgkmcnt(0)" ::: "memory");
        asm volatile("s_barrier" ::: "memory");
    }
    __syncthreads();

    // ---------- k-half reduction; pre+bias -> per-batch [64][64] bf16 ----------
    if (kh == 0) {
        #pragma unroll
        for (int m = 0; m < 4; ++m)
            #pragma unroll
            for (int n = 0; n < 4; ++n)
                *(f32x4*)(lds + bn * 16384 + ((m * 4 + n) * 64 + lane) * 16) = acc[m][n];
    }
    __syncthreads();
    if (kh == 1) {
        #pragma unroll
        for (int m = 0; m < 4; ++m)
            #pragma unroll
            for (int n = 0; n < 4; ++n)
                acc[m][n] += *(const f32x4*)(lds + bn * 16384 + ((m * 4 + n) * 64 + lane) * 16);
        char* const dst = pre + bn * 8192;
        #pragma unroll
        for (int m = 0; m < 4; ++m)
            #pragma unroll
            for (int n = 0; n < 4; ++n) {
                const int col = n * 16 + lr;
                #pragma unroll
                for (int r = 0; r < 4; ++r) {
                    const int row = m * 16 + lg * 4 + r;
                    const float bs = bias[orow0 + row];
                    *(__bf16*)(dst + row * 128 + ((2 * col) ^ ((row & 7) << 4))) =
                        bfc(acc[m][n][r] + bs);
                }
            }
    }
    __syncthreads();

    // ---------- epilogue on 128 rows (2 batches x 64) ----------
    const int wm = wv >> 1, wn = wv & 1;

    // T = relu(info @ fc1W^T + fc1b) -> T_lds [128][64] swizzled
    {
        const int row = tid >> 1;                 // 0..127
        const int j0 = (tid & 1) * 32;
        const int bb = batch0 + (row >> 6);
        const int g = bb * DOUT + orow0 + (row & 63);
        const float lv = lb[g], uv = ub[g];
        const float lt = fminf(lv, 0.f), ut = fmaxf(uv, 0.f);
        const float diff = ut - lt;
        const float urr = ut / (diff + 1e-8f);
        const float lrr = 1.f - urr, i3 = ps[g], i4 = ss[g];
        #pragma unroll
        for (int c = 0; c < 4; ++c) {
            bf16x8 v;
            #pragma unroll
            for (int jj = 0; jj < 8; ++jj) {
                const int j = j0 + c * 8 + jj;
                const float* w = fc1W + j * 5;
                const float tv = fc1b[j] + urr * w[0] + lrr * w[1] + diff * w[2]
                               + i3 * w[3] + i4 * w[4];
                v[jj] = bfc(fmaxf(tv, 0.f));
            }
            *(bf16x8*)(T_lds + aoff(row, (j0 >> 3) + c)) = v;
        }
    }
    __syncthreads();

    // H = T @ fc11W^T + fc11b -> per-batch H tiles
    {
        f32x4 hacc[4][2];
        #pragma unroll
        for (int m = 0; m < 4; ++m) { hacc[m][0] = z; hacc[m][1] = z; }
        #pragma unroll
        for (int ks = 0; ks < 2; ++ks) {
            bf16x8 a[4];
            #pragma unroll
            for (int m = 0; m < 4; ++m)
                a[m] = *(const bf16x8*)(T_lds + aoff(wm * 64 + m * 16 + lr, ks * 4 + lg));
            #pragma unroll
            for (int n = 0; n < 2; ++n) {
                const int j = wn * 32 + n * 16 + lr;
                const bf16x8 bw = *(const bf16x8*)(fc11bf + (size_t)j * 64 + ks * 32 + lg * 8);
                #pragma unroll
                for (int m = 0; m < 4; ++m)
                    hacc[m][n] = __builtin_amdgcn_mfma_f32_16x16x32_bf16(a[m], bw, hacc[m][n], 0, 0, 0);
            }
        }
        char* const Hq = H_lds + wm * 8192;
        #pragma unroll
        for (int n = 0; n < 2; ++n) {
            const int j = wn * 32 + n * 16 + lr;
            const float bj = fc11b[j];
            #pragma unroll
            for (int m = 0; m < 4; ++m)
                #pragma unroll
                for (int r = 0; r < 4; ++r) {
                    const int row = m * 16 + lg * 4 + r;   // local 0..63
                    *(__bf16*)(Hq + row * 128 + ((2 * j) ^ ((row & 7) << 4))) =
                        bfc(hacc[m][n][r] + bj);
                }
        }
    }
    __syncthreads();

    // U = relu([pre|H] @ fc2W^T + fc2b) -> T region (T dead)
    {
        f32x4 uacc[4][2];
        #pragma unroll
        for (int m = 0; m < 4; ++m) { uacc[m][0] = z; uacc[m][1] = z; }
        #pragma unroll
        for (int ks = 0; ks < 4; ++ks) {
            const char* base = ((ks < 2) ? pre : H_lds) + wm * 8192;
            const int kb = ((ks & 1) * 64 + lg * 16);
            bf16x8 a[4];
            #pragma unroll
            for (int m = 0; m < 4; ++m) {
                const int row = m * 16 + lr;
                a[m] = *(const bf16x8*)(base + row * 128 + (kb ^ ((row & 7) << 4)));
            }
            #pragma unroll
            for (int n = 0; n < 2; ++n) {
                const int j = wn * 32 + n * 16 + lr;
                const bf16x8 bw = *(const bf16x8*)(fc2bf + (size_t)j * 128 + ks * 32 + lg * 8);
                #pragma unroll
                for (int m = 0; m < 4; ++m)
                    uacc[m][n] = __builtin_amdgcn_mfma_f32_16x16x32_bf16(a[m], bw, uacc[m][n], 0, 0, 0);
            }
        }
        __syncthreads();
        #pragma unroll
        for (int n = 0; n < 2; ++n) {
            const int j = wn * 32 + n * 16 + lr;
            const float bj = fc2b[j];
            #pragma unroll
            for (int m = 0; m < 4; ++m)
                #pragma unroll
                for (int r = 0; r < 4; ++r) {
                    const int row = wm * 64 + m * 16 + lg * 4 + r;   // 0..127
                    *(__bf16*)(T_lds + row * 128 + ((2 * j) ^ ((row & 7) << 4))) =
                        bfc(fmaxf(uacc[m][n][r] + bj, 0.f));
                }
        }
    }
    __syncthreads();

    // out = (U @ fc21W^T + fc21b) * mask ; WT staging -> H region
    {
        f32x4 oacc[4][2];
        #pragma unroll
        for (int m = 0; m < 4; ++m) { oacc[m][0] = z; oacc[m][1] = z; }
        #pragma unroll
        for (int ks = 0; ks < 2; ++ks) {
            bf16x8 a[4];
            #pragma unroll
            for (int m = 0; m < 4; ++m)
                a[m] = *(const bf16x8*)(T_lds + aoff(wm * 64 + m * 16 + lr, ks * 4 + lg));
            #pragma unroll
            for (int n = 0; n < 2; ++n) {
                const int j = wn * 32 + n * 16 + lr;
                const bf16x8 bw = *(const bf16x8*)(fc21bf + (size_t)j * 64 + ks * 32 + lg * 8);
                #pragma unroll
                for (int m = 0; m < 4; ++m)
                    oacc[m][n] = __builtin_amdgcn_mfma_f32_16x16x32_bf16(a[m], bw, oacc[m][n], 0, 0, 0);
            }
        }
        const int bb = batch0 + wm;
        #pragma unroll
        for (int n = 0; n < 2; ++n) {
            const int j = wn * 32 + n * 16 + lr;
            const float bj = fc21b[j];
            #pragma unroll
            for (int m = 0; m < 4; ++m)
                #pragma unroll
                for (int r = 0; r < 4; ++r) {
                    const int row = m * 16 + lg * 4 + r;    // local 0..63
                    const int g = bb * DOUT + orow0 + row;
                    const float o = (oacc[m][n][r] + bj) * mask[g];
                    out[(size_t)g * 64 + j] = o;
                    if (WRITE_T)
                        *(__bf16*)(H_lds + wm * 8192 + j * 128 +
                                   ((2 * row) ^ ((j & 7) << 4))) = bfc(o);
                }
        }
    }
    if (WRITE_T) {
        __syncthreads();
        // emit frag-ordered tiles: 2 batches x 512 chunks
        #pragma unroll
        for (int i = 0; i < 4; ++i) {
            const int idx = i * 256 + tid;          // 0..1023
            const int qq = idx >> 9, rr = idx & 511;
            const int ks = rr >> 8, n = (rr >> 6) & 3, ln = rr & 63;
            const int j = n * 16 + (ln & 15);
            const int k = ks * 32 + (ln >> 4) * 8;
            const bf16x8 v = *(const bf16x8*)(H_lds + qq * 8192 + j * 128 +
                                              ((2 * k) ^ ((j & 7) << 4)));
            const int bb = batch0 + qq;
            *(bf16x8*)(wsT + ((size_t)bb * 64 + panel) * 8192 +
                       ks * 4096 + n * 1024 + ln * 16) = v;
        }
    }
#undef KT
}

extern "C" void kernel_launch(void* const* d_in, const int* in_sizes, int n_in,
                              void* d_out, int out_size, void* d_ws, size_t ws_size,
                              hipStream_t stream) {
    const float* mu0   = (const float*)d_in[0];
    const float* lb1   = (const float*)d_in[1];
    const float* ub1   = (const float*)d_in[2];
    const float* lb2   = (const float*)d_in[3];
    const float* ub2   = (const float*)d_in[4];
    const float* ps1   = (const float*)d_in[5];
    const float* ss1   = (const float*)d_in[6];
    const float* ps2   = (const float*)d_in[7];
    const float* ss2   = (const float*)d_in[8];
    const float* mask1 = (const float*)d_in[9];
    const float* mask2 = (const float*)d_in[10];
    const float* W1    = (const float*)d_in[11];
    const float* b1    = (const float*)d_in[12];
    const float* W2    = (const float*)d_in[13];
    const float* b2    = (const float*)d_in[14];
    const float* fc1W  = (const float*)d_in[15];
    const float* fc1b  = (const float*)d_in[16];
    const float* fc11W = (const float*)d_in[17];
    const float* fc11b = (const float*)d_in[18];
    const float* fc2W  = (const float*)d_in[19];
    const float* fc2b  = (const float*)d_in[20];
    const float* fc21W = (const float*)d_in[21];
    const float* fc21b = (const float*)d_in[22];

    char* ws = (char*)d_ws;
    float* mu1 = (float*)d_out;
    float* mu2 = (float*)d_out + (size_t)16 * 4096 * 64;
    const __bf16* fc11bf = (const __bf16*)(ws + WS_SM);
    const __bf16* fc2bf  = (const __bf16*)(ws + WS_SM) + 4096;
    const __bf16* fc21bf = (const __bf16*)(ws + WS_SM) + 12288;

    prepass_kernel<<<576, 256, 0, stream>>>(mu0, fc11W, fc2W, fc21W, ws);

    layer_kernel<2048, true><<<512, 256, 0, stream>>>(
        W1, b1, ws + WS_MU0, lb1, ub1, ps1, ss1, mask1,
        fc1W, fc1b, fc11bf, fc11b, fc2bf, fc2b, fc21bf, fc21b,
        mu1, ws + WS_MU1);

    layer_kernel<4096, false><<<512, 256, 0, stream>>>(
        W2, b2, ws + WS_MU1, lb2, ub2, ps2, ss2, mask2,
        fc1W, fc1b, fc11bf, fc11b, fc2bf, fc2b, fc21bf, fc21b,
        mu2, nullptr);
}

// Round 13
// 114.712 us; speedup vs baseline: 1.5164x; 1.4170x over previous
//
#include <hip/hip_runtime.h>
#include <hip/hip_bf16.h>

// EmbedLayerUpdate, round 12.
// Bigger tiles to cut on-chip traffic: block = 128 rows x 2 batches,
// 8 waves (512 thr) = (k-half) x (row-group) x (batch), grid 256 (1/CU,
// 2 waves/SIMD). NO k-rotation (round 10/11 lesson: lockstep = L2 coupling).
// Round-8 pipeline: 2-deep prefetch, 1 s_barrier/iter, counted vmcnt(8).
// B = frag-ordered bf16 in ws (global->VGPR). A = fp32->cvt->swizzled LDS dbuf.
// Epilogue: k-half reduce via LDS, then 2 batch-passes of the proven relu-block.

#define DOUT 4096
typedef __bf16 bf16x8 __attribute__((ext_vector_type(8)));
typedef __bf16 bf16x4 __attribute__((ext_vector_type(4)));
typedef float  f32x4  __attribute__((ext_vector_type(4)));

__device__ __forceinline__ __bf16 bfc(float x) { return (__bf16)x; }

__device__ __forceinline__ bf16x4 cvt4(const float4 a) {
    bf16x4 r;
    r[0]=bfc(a.x); r[1]=bfc(a.y); r[2]=bfc(a.z); r[3]=bfc(a.w);
    return r;
}

// 128-byte rows (64 bf16): XOR-swizzle 16B chunks with row&7
__device__ __forceinline__ int aoff(int r, int c16) {
    return (r << 7) + ((c16 << 4) ^ ((r & 7) << 4));
}

#define WS_MU0 0
#define WS_MU1 (4u << 20)
#define WS_SM  (12u << 20)

// ---- prepass: mu0 -> frag-ordered bf16 tiles; small weights -> bf16 ----
__global__ __launch_bounds__(256)
void prepass_kernel(const float* __restrict__ mu0, const float* __restrict__ fc11W,
                    const float* __restrict__ fc2W, const float* __restrict__ fc21W,
                    char* __restrict__ ws)
{
    const int blk = blockIdx.x, t = threadIdx.x;
    if (blk < 512) {
        const int b = blk >> 5, kt = blk & 31;
        const int p = t & 63, kc = t >> 6;       // kc 0..3: 16 k each
        const float* src = mu0 + ((size_t)b * 2048 + kt * 64 + kc * 16) * 64 + p;
        char* tile = ws + WS_MU0 + ((size_t)b * 32 + kt) * 8192;
        float v[16];
        #pragma unroll
        for (int i = 0; i < 16; ++i) v[i] = src[(size_t)i * 64];
        bf16x8 o0, o1;
        #pragma unroll
        for (int i = 0; i < 8; ++i) { o0[i] = bfc(v[i]); o1[i] = bfc(v[8 + i]); }
        const int n = p >> 4, ks = kc >> 1;
        const int l0 = (((kc & 1) * 2) << 4) | (p & 15);
        const int l1 = (((kc & 1) * 2 + 1) << 4) | (p & 15);
        *(bf16x8*)(tile + ks * 4096 + n * 1024 + l0 * 16) = o0;
        *(bf16x8*)(tile + ks * 4096 + n * 1024 + l1 * 16) = o1;
    } else {
        const int idx = (blk - 512) * 256 + t;
        __bf16* dst = (__bf16*)(ws + WS_SM);
        if (idx < 4096)        dst[idx] = bfc(fc11W[idx]);
        else if (idx < 12288)  dst[idx] = bfc(fc2W[idx - 4096]);
        else                   dst[idx] = bfc(fc21W[idx - 12288]);
    }
}

// A: wave-instruction = 4 contiguous 256B row segments (rows tid>>4 + 32q)
#define LOADA(dst, kt_) { const float* s_ = aSrc + (size_t)(kt_) * 64;          \
    dst[0] = *(const float4*)s_;                                                \
    dst[1] = *(const float4*)(s_ + 32 * K);                                     \
    dst[2] = *(const float4*)(s_ + 64 * K);                                     \
    dst[3] = *(const float4*)(s_ + 96 * K); }

#define WRITEA(buf, set) {                                                      \
    *(bf16x4*)((buf) + awb)         = cvt4(set[0]);                             \
    *(bf16x4*)((buf) + awb + 4096)  = cvt4(set[1]);                             \
    *(bf16x4*)((buf) + awb + 8192)  = cvt4(set[2]);                             \
    *(bf16x4*)((buf) + awb + 12288) = cvt4(set[3]); }

#define LOADB(dst, kt_) { const char* bp_ = bW + (size_t)(kt_) * 8192 + lane * 16; \
    _Pragma("unroll")                                                            \
    for (int n_ = 0; n_ < 4; ++n_) dst[n_] = *(const bf16x8*)(bp_ + n_ * 1024); }

#define MFMAS(Abuf, bset) {                                                      \
    bf16x8 af_[4];                                                               \
    _Pragma("unroll")                                                            \
    for (int m_ = 0; m_ < 4; ++m_)                                               \
        af_[m_] = *(const bf16x8*)((Abuf) + aoff(mg * 64 + m_ * 16 + lr, khc + lg)); \
    __builtin_amdgcn_s_setprio(1);                                               \
    _Pragma("unroll")                                                            \
    for (int m_ = 0; m_ < 4; ++m_)                                               \
        _Pragma("unroll")                                                        \
        for (int n_ = 0; n_ < 4; ++n_)                                           \
            acc[m_][n_] = __builtin_amdgcn_mfma_f32_16x16x32_bf16(               \
                af_[m_], bset[n_], acc[m_][n_], 0, 0, 0);                        \
    __builtin_amdgcn_s_setprio(0); }

// ---------------- layer kernel ----------------
template <int K, bool WRITE_T>
__global__ __launch_bounds__(512, 2)
void layer_kernel(const float* __restrict__ W, const float* __restrict__ bias,
                  const char* __restrict__ wsB,
                  const float* __restrict__ lb, const float* __restrict__ ub,
                  const float* __restrict__ ps, const float* __restrict__ ss,
                  const float* __restrict__ mask,
                  const float* __restrict__ fc1W, const float* __restrict__ fc1b,
                  const __bf16* __restrict__ fc11bf, const float* __restrict__ fc11b,
                  const __bf16* __restrict__ fc2bf, const float* __restrict__ fc2b,
                  const __bf16* __restrict__ fc21bf, const float* __restrict__ fc21b,
                  float* __restrict__ out, char* __restrict__ wsT)
{
    constexpr int NT = K / 64;
    __shared__ __align__(16) char lds[65536];
    // main: A dbuf @0/16K (16KB each: 128 rows x 64k bf16).
    // post:  red rounds @0..32K; pre @32K(16KB/batch x2).
    // pass:  T @0 (16KB), H @16K (16KB), U -> T, WT staging -> H.

    const int tid = threadIdx.x;
    const int lane = tid & 63, wv = tid >> 6;
    const int kh = wv >> 2;                      // k-half
    const int mg = (wv >> 1) & 1;                // row-group (64 rows)
    const int bn = wv & 1;                       // batch-in-block
    const int khc = kh * 4;
    const int lr = lane & 15, lg = lane >> 4;

    // XCD swizzle: 256 = 8 xcd * 32; XCD gets 4 panels x 8 bgroups
    const int id = blockIdx.x;
    const int vid = (id & 7) * 32 + (id >> 3);
    const int panel = vid >> 3;                  // 0..31 (128-row panels)
    const int bgroup = vid & 7;                  // 0..7 (2 batches each)
    const int orow0 = panel * 128;
    const int batch0 = bgroup * 2;

    const char* bW = wsB + ((size_t)(batch0 + bn) * NT) * 8192 + kh * 4096;

    // A loader: base row = tid>>4 (0..31; +32 per pass), col = tid&15 (float4).
    const int arow = tid >> 4, acol = tid & 15;
    const float* aSrc = W + (size_t)(orow0 + arow) * K + acol * 4;
    const int awb = arow * 128 + ((acol * 8) ^ ((arow & 7) << 4));

    const f32x4 z = {0.f, 0.f, 0.f, 0.f};
    f32x4 acc[4][4];
    #pragma unroll
    for (int m = 0; m < 4; ++m)
        #pragma unroll
        for (int n = 0; n < 4; ++n) acc[m][n] = z;

    float4 aR0[4], aR1[4];
    bf16x8 bR0[4], bR1[4];

    // ---------- prologue ----------
    LOADA(aR0, 0); LOADB(bR0, 0);
    LOADA(aR1, 1); LOADB(bR1, 1);
    asm volatile("s_waitcnt vmcnt(8)" ::: "memory");   // aR0,bR0 landed
    WRITEA(lds, aR0);
    asm volatile("s_waitcnt lgkmcnt(0)" ::: "memory");
    asm volatile("s_barrier" ::: "memory");

    // ---------- main loop (unroll 2, static reg sets) ----------
    for (int t = 0; t < NT; t += 2) {
        // even: consume buf0/bR0
        if (t + 2 < NT) LOADA(aR0, t + 2);
        MFMAS(lds, bR0);
        if (t + 2 < NT) LOADB(bR0, t + 2);
        if (t + 2 < NT) asm volatile("s_waitcnt vmcnt(8)" ::: "memory");
        else            asm volatile("s_waitcnt vmcnt(0)" ::: "memory");
        WRITEA(lds + 16384, aR1);                      // A(t+1)
        asm volatile("s_waitcnt lgkmcnt(0)" ::: "memory");
        asm volatile("s_barrier" ::: "memory");
        // odd: consume buf1/bR1
        if (t + 3 < NT) LOADA(aR1, t + 3);
        MFMAS(lds + 16384, bR1);
        if (t + 3 < NT) LOADB(bR1, t + 3);
        if (t + 3 < NT) asm volatile("s_waitcnt vmcnt(8)" ::: "memory");
        else            asm volatile("s_waitcnt vmcnt(0)" ::: "memory");
        if (t + 2 < NT) { WRITEA(lds, aR0); }          // A(t+2)
        asm volatile("s_waitcnt lgkmcnt(0)" ::: "memory");
        asm volatile("s_barrier" ::: "memory");
    }
    __syncthreads();

    // ---------- k-half reduction (2 rounds of 32KB) + pre bf16 @32K ----------
    #pragma unroll
    for (int r = 0; r < 2; ++r) {
        if (kh == 0 && bn == r) {
            #pragma unroll
            for (int m = 0; m < 4; ++m)
                #pragma unroll
                for (int n = 0; n < 4; ++n)
                    *(f32x4*)(lds + mg * 16384 + ((m * 4 + n) * 64 + lane) * 16) = acc[m][n];
        }
        __syncthreads();
        if (kh == 1 && bn == r) {
            char* const dst = lds + 32768 + r * 16384;
            #pragma unroll
            for (int m = 0; m < 4; ++m)
                #pragma unroll
                for (int n = 0; n < 4; ++n) {
                    const f32x4 s = *(const f32x4*)(lds + mg * 16384 + ((m * 4 + n) * 64 + lane) * 16);
                    const int col = n * 16 + lr;
                    #pragma unroll
                    for (int rr = 0; rr < 4; ++rr) {
                        const int row = mg * 64 + m * 16 + lg * 4 + rr;
                        const float bs = bias[orow0 + row];
                        *(__bf16*)(dst + row * 128 + ((2 * col) ^ ((row & 7) << 4))) =
                            bfc(acc[m][n][rr] + s[rr] + bs);
                    }
                }
        }
        __syncthreads();
    }

    // ---------- epilogue: 2 passes (one batch each), 8 waves over 128 rows ----------
    char* const T_lds = lds;
    char* const H_lds = lds + 16384;
    const int mh = wv >> 1;                      // 0..3: 32-row group
    const int wn = wv & 1;                       // j-half

    for (int p = 0; p < 2; ++p) {
        const char* const preB = lds + 32768 + p * 16384;
        const int bb = batch0 + p;

        // T = relu(info @ fc1W^T + fc1b) -> T_lds [128][64] swizzled
        {
            const int row = tid >> 2;                 // 0..127
            const int jq = tid & 3;
            const int g = bb * DOUT + orow0 + row;
            const float lv = lb[g], uv = ub[g];
            const float lt = fminf(lv, 0.f), ut = fmaxf(uv, 0.f);
            const float diff = ut - lt;
            const float urr = ut / (diff + 1e-8f);
            const float lrr = 1.f - urr, i3 = ps[g], i4 = ss[g];
            #pragma unroll
            for (int c = 0; c < 2; ++c) {
                bf16x8 v;
                #pragma unroll
                for (int jj = 0; jj < 8; ++jj) {
                    const int j = jq * 16 + c * 8 + jj;
                    const float* w = fc1W + j * 5;
                    const float tv = fc1b[j] + urr * w[0] + lrr * w[1] + diff * w[2]
                                   + i3 * w[3] + i4 * w[4];
                    v[jj] = bfc(fmaxf(tv, 0.f));
                }
                *(bf16x8*)(T_lds + aoff(row, jq * 2 + c)) = v;
            }
        }
        __syncthreads();

        // H = T @ fc11W^T + fc11b -> H_lds
        {
            f32x4 hacc[2][2];
            #pragma unroll
            for (int m = 0; m < 2; ++m) { hacc[m][0] = z; hacc[m][1] = z; }
            #pragma unroll
            for (int ks = 0; ks < 2; ++ks) {
                bf16x8 a[2];
                #pragma unroll
                for (int m = 0; m < 2; ++m)
                    a[m] = *(const bf16x8*)(T_lds + aoff(mh * 32 + m * 16 + lr, ks * 4 + lg));
                #pragma unroll
                for (int n = 0; n < 2; ++n) {
                    const int j = wn * 32 + n * 16 + lr;
                    const bf16x8 bw = *(const bf16x8*)(fc11bf + (size_t)j * 64 + ks * 32 + lg * 8);
                    #pragma unroll
                    for (int m = 0; m < 2; ++m)
                        hacc[m][n] = __builtin_amdgcn_mfma_f32_16x16x32_bf16(a[m], bw, hacc[m][n], 0, 0, 0);
                }
            }
            #pragma unroll
            for (int n = 0; n < 2; ++n) {
                const int j = wn * 32 + n * 16 + lr;
                const float bj = fc11b[j];
                #pragma unroll
                for (int m = 0; m < 2; ++m)
                    #pragma unroll
                    for (int rr = 0; rr < 4; ++rr) {
                        const int row = mh * 32 + m * 16 + lg * 4 + rr;
                        *(__bf16*)(H_lds + row * 128 + ((2 * j) ^ ((row & 7) << 4))) =
                            bfc(hacc[m][n][rr] + bj);
                    }
            }
        }
        __syncthreads();

        // U = relu([pre|H] @ fc2W^T + fc2b) -> T region (T dead)
        {
            f32x4 uacc[2][2];
            #pragma unroll
            for (int m = 0; m < 2; ++m) { uacc[m][0] = z; uacc[m][1] = z; }
            #pragma unroll
            for (int ks = 0; ks < 4; ++ks) {
                const char* base = (ks < 2) ? preB : H_lds;
                const int kb = ((ks & 1) * 64 + lg * 16);
                bf16x8 a[2];
                #pragma unroll
                for (int m = 0; m < 2; ++m) {
                    const int row = mh * 32 + m * 16 + lr;
                    a[m] = *(const bf16x8*)(base + row * 128 + (kb ^ ((row & 7) << 4)));
                }
                #pragma unroll
                for (int n = 0; n < 2; ++n) {
                    const int j = wn * 32 + n * 16 + lr;
                    const bf16x8 bw = *(const bf16x8*)(fc2bf + (size_t)j * 128 + ks * 32 + lg * 8);
                    #pragma unroll
                    for (int m = 0; m < 2; ++m)
                        uacc[m][n] = __builtin_amdgcn_mfma_f32_16x16x32_bf16(a[m], bw, uacc[m][n], 0, 0, 0);
                }
            }
            __syncthreads();   // all T/H/pre reads done before overwriting T
            #pragma unroll
            for (int n = 0; n < 2; ++n) {
                const int j = wn * 32 + n * 16 + lr;
                const float bj = fc2b[j];
                #pragma unroll
                for (int m = 0; m < 2; ++m)
                    #pragma unroll
                    for (int rr = 0; rr < 4; ++rr) {
                        const int row = mh * 32 + m * 16 + lg * 4 + rr;
                        *(__bf16*)(T_lds + row * 128 + ((2 * j) ^ ((row & 7) << 4))) =
                            bfc(fmaxf(uacc[m][n][rr] + bj, 0.f));
                    }
            }
        }
        __syncthreads();

        // out = (U @ fc21W^T + fc21b) * mask ; WT staging -> H region
        {
            f32x4 oacc[2][2];
            #pragma unroll
            for (int m = 0; m < 2; ++m) { oacc[m][0] = z; oacc[m][1] = z; }
            #pragma unroll
            for (int ks = 0; ks < 2; ++ks) {
                bf16x8 a[2];
                #pragma unroll
                for (int m = 0; m < 2; ++m)
                    a[m] = *(const bf16x8*)(T_lds + aoff(mh * 32 + m * 16 + lr, ks * 4 + lg));
                #pragma unroll
                for (int n = 0; n < 2; ++n) {
                    const int j = wn * 32 + n * 16 + lr;
                    const bf16x8 bw = *(const bf16x8*)(fc21bf + (size_t)j * 64 + ks * 32 + lg * 8);
                    #pragma unroll
                    for (int m = 0; m < 2; ++m)
                        oacc[m][n] = __builtin_amdgcn_mfma_f32_16x16x32_bf16(a[m], bw, oacc[m][n], 0, 0, 0);
                }
            }
            #pragma unroll
            for (int n = 0; n < 2; ++n) {
                const int j = wn * 32 + n * 16 + lr;
                const float bj = fc21b[j];
                #pragma unroll
                for (int m = 0; m < 2; ++m)
                    #pragma unroll
                    for (int rr = 0; rr < 4; ++rr) {
                        const int row = mh * 32 + m * 16 + lg * 4 + rr;   // 0..127
                        const int g = bb * DOUT + orow0 + row;
                        const float o = (oacc[m][n][rr] + bj) * mask[g];
                        out[(size_t)g * 64 + j] = o;
                        if (WRITE_T)
                            *(__bf16*)(H_lds + (row >> 6) * 8192 + j * 128 +
                                       ((2 * (row & 63)) ^ ((j & 7) << 4))) = bfc(o);
                    }
            }
        }
        if (WRITE_T) {
            __syncthreads();
            // emit 2 frag-ordered 64-row tiles (1024 chunks, 512 threads x 2)
            #pragma unroll
            for (int i = 0; i < 2; ++i) {
                const int idx = i * 512 + tid;          // 0..1023
                const int qq = idx >> 9, rr = idx & 511;
                const int ks = rr >> 8, n = (rr >> 6) & 3, ln = rr & 63;
                const int j = n * 16 + (ln & 15);
                const int k = ks * 32 + (ln >> 4) * 8;
                const bf16x8 v = *(const bf16x8*)(H_lds + qq * 8192 + j * 128 +
                                                  ((2 * k) ^ ((j & 7) << 4)));
                *(bf16x8*)(wsT + ((size_t)bb * 64 + (orow0 >> 6) + qq) * 8192 +
                           ks * 4096 + n * 1024 + ln * 16) = v;
            }
        }
        __syncthreads();
    }
}

extern "C" void kernel_launch(void* const* d_in, const int* in_sizes, int n_in,
                              void* d_out, int out_size, void* d_ws, size_t ws_size,
                              hipStream_t stream) {
    const float* mu0   = (const float*)d_in[0];
    const float* lb1   = (const float*)d_in[1];
    const float* ub1   = (const float*)d_in[2];
    const float* lb2   = (const float*)d_in[3];
    const float* ub2   = (const float*)d_in[4];
    const float* ps1   = (const float*)d_in[5];
    const float* ss1   = (const float*)d_in[6];
    const float* ps2   = (const float*)d_in[7];
    const float* ss2   = (const float*)d_in[8];
    const float* mask1 = (const float*)d_in[9];
    const float* mask2 = (const float*)d_in[10];
    const float* W1    = (const float*)d_in[11];
    const float* b1    = (const float*)d_in[12];
    const float* W2    = (const float*)d_in[13];
    const float* b2    = (const float*)d_in[14];
    const float* fc1W  = (const float*)d_in[15];
    const float* fc1b  = (const float*)d_in[16];
    const float* fc11W = (const float*)d_in[17];
    const float* fc11b = (const float*)d_in[18];
    const float* fc2W  = (const float*)d_in[19];
    const float* fc2b  = (const float*)d_in[20];
    const float* fc21W = (const float*)d_in[21];
    const float* fc21b = (const float*)d_in[22];

    char* ws = (char*)d_ws;
    float* mu1 = (float*)d_out;
    float* mu2 = (float*)d_out + (size_t)16 * 4096 * 64;
    const __bf16* fc11bf = (const __bf16*)(ws + WS_SM);
    const __bf16* fc2bf  = (const __bf16*)(ws + WS_SM) + 4096;
    const __bf16* fc21bf = (const __bf16*)(ws + WS_SM) + 12288;

    prepass_kernel<<<576, 256, 0, stream>>>(mu0, fc11W, fc2W, fc21W, ws);

    layer_kernel<2048, true><<<256, 512, 0, stream>>>(
        W1, b1, ws + WS_MU0, lb1, ub1, ps1, ss1, mask1,
        fc1W, fc1b, fc11bf, fc11b, fc2bf, fc2b, fc21bf, fc21b,
        mu1, ws + WS_MU1);

    layer_kernel<4096, false><<<256, 512, 0, stream>>>(
        W2, b2, ws + WS_MU1, lb2, ub2, ps2, ss2, mask2,
        fc1W, fc1b, fc11bf, fc11b, fc2bf, fc2b, fc21bf, fc21b,
        mu2, nullptr);
}